// Round 10
// baseline (332.198 us; speedup 1.0000x reference)
//
#include <hip/hip_runtime.h>
#include <math.h>

#define BB    4
#define TT    1024
#define EE    1024
#define HH    16
#define HDIM  64
#define SS    2048
#define MROWS 4096
#define SCALEQ 0.125f

typedef short  s8v  __attribute__((ext_vector_type(8)));
typedef float  f4v  __attribute__((ext_vector_type(4)));

__device__ __forceinline__ unsigned short f2bf(float f) {
    union { float f; unsigned u; } c; c.f = f;
    unsigned u = c.u + 0x7FFFu + ((c.u >> 16) & 1u);
    return (unsigned short)(u >> 16);
}
__device__ __forceinline__ float bf2f(unsigned short h) {
    union { unsigned u; float f; } c; c.u = ((unsigned)h) << 16;
    return c.f;
}

__device__ __forceinline__ void async16(const void* g, void* l) {
    __builtin_amdgcn_global_load_lds(
        (const __attribute__((address_space(1))) unsigned int*)g,
        (__attribute__((address_space(3))) unsigned int*)l,
        16, 0, 0);
}

// ---------------------------------------------------------------------------
// Fused fp32->bf16 convert: x, Wq, Wk, Wv, Wo, mask. (verified R5-R9)
// ---------------------------------------------------------------------------
__global__ __launch_bounds__(256) void cvt6_kernel(
    const float* __restrict__ x,  const float* __restrict__ wq,
    const float* __restrict__ wk, const float* __restrict__ wv,
    const float* __restrict__ wo, const float* __restrict__ mk,
    unsigned short* __restrict__ xb,  unsigned short* __restrict__ wqb,
    unsigned short* __restrict__ wkb, unsigned short* __restrict__ wvb,
    unsigned short* __restrict__ wob, unsigned short* __restrict__ mbb)
{
    const int total = 3670016;
    int i = blockIdx.x * 256 + threadIdx.x;
    const int stride = gridDim.x * 256;
    for (; i < total; i += stride) {
        const float* s; unsigned short* d; int off;
        if (i < 1048576)      { s = x;  d = xb;  off = i; }
        else if (i < 1310720) { s = wq; d = wqb; off = i - 1048576; }
        else if (i < 1835008) { s = wk; d = wkb; off = i - 1310720; }
        else if (i < 2359296) { s = wv; d = wvb; off = i - 1835008; }
        else if (i < 2621440) { s = wo; d = wob; off = i - 2359296; }
        else                  { s = mk; d = mbb; off = i - 2621440; }
        float4 v = ((const float4*)s)[off];
        ushort4 o;
        o.x = f2bf(v.x); o.y = f2bf(v.y); o.z = f2bf(v.z); o.w = f2bf(v.w);
        ((ushort4*)d)[off] = o;
    }
}

// ---------------------------------------------------------------------------
// Fused Q+K+V projection v2: twin-buffer K-loop (2x BK=32 tiles per barrier
// pair -> 16 super-iters, 32 barriers). LDS 32 KB; launch_bounds(256,5) ->
// 5 blocks/CU -> grid 1280 fully resident in one shot.
//   gid<256: Q -> qp plain; gid<768: K -> kp [B,H,S,HD]; else V^T -> vt.
// ---------------------------------------------------------------------------
__global__ __launch_bounds__(256, 5) void gemm_qkv_kernel(
    const unsigned short* __restrict__ X,
    const unsigned short* __restrict__ Wq, const unsigned short* __restrict__ Wk,
    const unsigned short* __restrict__ Wv,
    const float* __restrict__ bq, const float* __restrict__ bk,
    const float* __restrict__ bv,
    unsigned short* __restrict__ qp, unsigned short* __restrict__ kp,
    unsigned short* __restrict__ vt)
{
    __shared__ __align__(16) unsigned short As[2][128 * 32];
    __shared__ __align__(16) unsigned short Bs[2][128 * 32];

    const int tid = threadIdx.x;
    const int lane = tid & 63, w = tid >> 6;
    const int wm = (w & 1) * 64, wn = (w >> 1) * 64;
    const int col16 = lane & 15, quad = lane >> 4;

    const int gid = blockIdx.x;
    int mode, mi, ni;
    const unsigned short *Ab, *Bb;
    if (gid < 256) {
        mode = 0; mi = gid >> 3; ni = gid & 7;
        Ab = X + (size_t)mi * 128 * EE;  Bb = Wq + (size_t)ni * 128 * EE;
    } else if (gid < 768) {
        int g = gid - 256; mode = 1; mi = g >> 4; ni = g & 15;
        Ab = X + (size_t)mi * 128 * EE;  Bb = Wk + (size_t)ni * 128 * EE;
    } else {
        int g = gid - 768; mode = 2; mi = g & 15; ni = g >> 4;
        Ab = Wv + (size_t)mi * 128 * EE; Bb = X + (size_t)ni * 128 * EE;
    }

    f4v acc[4][4];
#pragma unroll
    for (int i = 0; i < 4; ++i)
#pragma unroll
        for (int j = 0; j < 4; ++j) acc[i][j] = (f4v)0.0f;

    for (int k0 = 0; k0 < EE; k0 += 64) {
#pragma unroll
        for (int half = 0; half < 2; ++half)
#pragma unroll
            for (int it = 0; it < 2; ++it) {
                int f = (it * 4 + w) * 64 + lane;
                int r = f >> 2, g = (f & 3) * 8;
                async16(Ab + (size_t)r * EE + k0 + half * 32 + g,
                        As[half] + (it * 4 + w) * 512);
                async16(Bb + (size_t)r * EE + k0 + half * 32 + g,
                        Bs[half] + (it * 4 + w) * 512);
            }
        __syncthreads();
#pragma unroll
        for (int half = 0; half < 2; ++half) {
            s8v af[4], bf[4];
#pragma unroll
            for (int i = 0; i < 4; ++i)
                af[i] = *(const s8v*)(As[half] + (wm + i * 16 + col16) * 32 + quad * 8);
#pragma unroll
            for (int j = 0; j < 4; ++j)
                bf[j] = *(const s8v*)(Bs[half] + (wn + j * 16 + col16) * 32 + quad * 8);
#pragma unroll
            for (int i = 0; i < 4; ++i)
#pragma unroll
                for (int j = 0; j < 4; ++j)
                    acc[i][j] = __builtin_amdgcn_mfma_f32_16x16x32_bf16(
                        af[i], bf[j], acc[i][j], 0, 0, 0);
        }
        __syncthreads();
    }

#pragma unroll
    for (int j = 0; j < 4; ++j) {
        const int nl = wn + j * 16 + col16;
#pragma unroll
        for (int i = 0; i < 4; ++i) {
#pragma unroll
            for (int r = 0; r < 4; ++r) {
                const int ml = wm + i * 16 + quad * 4 + r;
                float c = acc[i][j][r];
                if (mode == 0) {
                    const int m = mi * 128 + ml, n = ni * 128 + nl;
                    qp[(size_t)m * EE + n] = f2bf((c + bq[n]) * SCALEQ);
                } else if (mode == 1) {
                    const int m = mi * 128 + ml, nk = ni * 128 + nl;
                    const int mm = nk >> 10, h = (nk >> 6) & 15, d = nk & 63;
                    const int b_ = m >> 10, t = m & 1023;
                    const int s = 2 * t + mm;
                    kp[((size_t)(b_ * HH + h) * SS + s) * HDIM + d] = f2bf(c + bk[nk]);
                } else {
                    const int f = mi * 128 + ml, tok = ni * 128 + nl;
                    const int mm = f >> 10, h = (f >> 6) & 15, d = f & 63;
                    const int b_ = tok >> 10, t = tok & 1023;
                    const int s = 2 * t + mm;
                    vt[((size_t)(b_ * HH + h) * HDIM + d) * SS + s] = f2bf(c + bv[f]);
                }
            }
        }
    }
}

// ---------------------------------------------------------------------------
// O-projection GEMM v2: 64x128 tile, twin-buffer K-loop (16 super-iters).
// LDS 24 KB, 512 blocks (2 rounds of 256 at 4/CU... fully pipelined).
// ---------------------------------------------------------------------------
__global__ __launch_bounds__(256, 4) void gemm_o64_kernel(
    const unsigned short* __restrict__ A, const unsigned short* __restrict__ W,
    const float* __restrict__ bias, float* __restrict__ Cout)
{
    __shared__ __align__(16) unsigned short As[2][64 * 32];
    __shared__ __align__(16) unsigned short Bs[2][128 * 32];

    const int tid = threadIdx.x;
    const int lane = tid & 63, w = tid >> 6;
    const int col16 = lane & 15, quad = lane >> 4;
    const int m0 = blockIdx.x * 64;
    const int n0 = blockIdx.y * 128;
    const unsigned short* Ab = A + (size_t)m0 * EE;
    const unsigned short* Bb = W + (size_t)n0 * EE;

    f4v acc[4][2];
#pragma unroll
    for (int i = 0; i < 4; ++i)
#pragma unroll
        for (int j = 0; j < 2; ++j) acc[i][j] = (f4v)0.0f;

    for (int k0 = 0; k0 < EE; k0 += 64) {
#pragma unroll
        for (int half = 0; half < 2; ++half) {
            {
                int r = tid >> 2, g = (tid & 3) * 8;
                async16(Ab + (size_t)r * EE + k0 + half * 32 + g, As[half] + w * 512);
            }
#pragma unroll
            for (int it = 0; it < 2; ++it) {
                int f = (it * 4 + w) * 64 + lane;
                int r = f >> 2, g = (f & 3) * 8;
                async16(Bb + (size_t)r * EE + k0 + half * 32 + g,
                        Bs[half] + (it * 4 + w) * 512);
            }
        }
        __syncthreads();
#pragma unroll
        for (int half = 0; half < 2; ++half) {
            s8v af[4], bf[2];
#pragma unroll
            for (int i = 0; i < 4; ++i)
                af[i] = *(const s8v*)(As[half] + (i * 16 + col16) * 32 + quad * 8);
#pragma unroll
            for (int j = 0; j < 2; ++j)
                bf[j] = *(const s8v*)(Bs[half] + (w * 32 + j * 16 + col16) * 32 + quad * 8);
#pragma unroll
            for (int i = 0; i < 4; ++i)
#pragma unroll
                for (int j = 0; j < 2; ++j)
                    acc[i][j] = __builtin_amdgcn_mfma_f32_16x16x32_bf16(
                        af[i], bf[j], acc[i][j], 0, 0, 0);
        }
        __syncthreads();
    }

#pragma unroll
    for (int j = 0; j < 2; ++j) {
        const int n = n0 + w * 32 + j * 16 + col16;
        const float bn = bias[n];
#pragma unroll
        for (int i = 0; i < 4; ++i)
#pragma unroll
            for (int r = 0; r < 4; ++r) {
                const int m = m0 + i * 16 + quad * 4 + r;
                Cout[(size_t)m * EE + n] = acc[i][j][r] + bn;
            }
    }
}

// ---------------------------------------------------------------------------
// Flash attention v6 — UNCHANGED from R9 (verified, absmax 2.44e-4).
// ---------------------------------------------------------------------------
__global__ __launch_bounds__(256, 4) void attn_mfma6_kernel(
    const unsigned short* __restrict__ Q, const unsigned short* __restrict__ Kh,
    const unsigned short* __restrict__ Vt, const unsigned short* __restrict__ Mb,
    unsigned short* __restrict__ O)
{
    constexpr int PT = 68;   // 136B pitch (R5-proven: 0 bank conflicts)
    __shared__ __align__(16) unsigned short Ks[64 * PT];
    __shared__ __align__(16) unsigned short Vs[64 * PT];  // V^T tile [d][s]
    __shared__ __align__(16) unsigned short Ms[64 * PT];  // mask [t][t2] bf16
    __shared__ __align__(16) unsigned short Ps[64 * PT];  // P [t][s], wave-private rows

    const int tid = threadIdx.x;
    const int lane = tid & 63, w = tid >> 6;
    const int col16 = lane & 15, quad = lane >> 4;

    const int gid = blockIdx.x;
    const int v = gid & 7, j = gid >> 3;
    const int bh = v * 8 + (j >> 4);
    const int t0 = (j & 15) * 64;
    const int b_ = bh >> 4, h = bh & 15;

    const unsigned short* Kb  = Kh + (size_t)bh * SS * HDIM;
    const unsigned short* Vb  = Vt + (size_t)bh * HDIM * SS;
    const unsigned short* Mbb = Mb + (size_t)b_ * TT * TT;
    const int myrow = (w * 16 + col16) * PT;

    const unsigned short* Qrow = Q + (size_t)(b_ * TT + t0 + w * 16 + col16) * EE + h * HDIM;
    s8v qf[2];
    qf[0] = *(const s8v*)(Qrow + quad * 8);
    qf[1] = *(const s8v*)(Qrow + 32 + quad * 8);

    f4v oacc[4];
#pragma unroll
    for (int jd = 0; jd < 4; ++jd) oacc[jd] = (f4v)0.0f;
    float mrun = -INFINITY, lrun = 0.0f;

    for (int s0 = 0; s0 < SS; s0 += 64) {
        const int t2b = s0 & (TT - 1);
        __syncthreads();  // (A)
#pragma unroll
        for (int st = 0; st < 2; ++st) {
            int idx = tid + st * 256;
            int r = idx >> 3, c = (idx & 7) * 8;
            *(uint4*)(Ks + r * PT + c) = *(const uint4*)(Kb + (size_t)(s0 + r) * HDIM + c);
            *(uint4*)(Vs + r * PT + c) = *(const uint4*)(Vb + (size_t)r * SS + s0 + c);
            *(uint4*)(Ms + r * PT + c) = *(const uint4*)(Mbb + (size_t)(t0 + r) * TT + t2b + c);
        }
        __syncthreads();  // (B)

        f4v sacc[4];
#pragma unroll
        for (int js = 0; js < 4; ++js) sacc[js] = (f4v)0.0f;
#pragma unroll
        for (int ks = 0; ks < 2; ++ks) {
            s8v bq_ = qf[ks];
#pragma unroll
            for (int js = 0; js < 4; ++js) {
                s8v ak = *(const s8v*)(Ks + (js * 16 + col16) * PT + ks * 32 + quad * 8);
                sacc[js] = __builtin_amdgcn_mfma_f32_16x16x32_bf16(ak, bq_, sacc[js], 0, 0, 0);
            }
        }

#pragma unroll
        for (int js = 0; js < 4; ++js) {
            uint2 mm = *(const uint2*)(Ms + myrow + js * 16 + quad * 4);
            sacc[js][0] += bf2f((unsigned short)(mm.x & 0xffff));
            sacc[js][1] += bf2f((unsigned short)(mm.x >> 16));
            sacc[js][2] += bf2f((unsigned short)(mm.y & 0xffff));
            sacc[js][3] += bf2f((unsigned short)(mm.y >> 16));
        }

        float tmax = -INFINITY;
#pragma unroll
        for (int js = 0; js < 4; ++js)
#pragma unroll
            for (int r = 0; r < 4; ++r) tmax = fmaxf(tmax, sacc[js][r]);
        tmax = fmaxf(tmax, __shfl_xor(tmax, 16));
        tmax = fmaxf(tmax, __shfl_xor(tmax, 32));
        const float mnew = fmaxf(mrun, tmax);
        const float scl = __expf(mrun - mnew);
        float rs = 0.0f;
#pragma unroll
        for (int js = 0; js < 4; ++js)
#pragma unroll
            for (int r = 0; r < 4; ++r) {
                float p = __expf(sacc[js][r] - mnew);
                sacc[js][r] = p;
                rs += p;
            }
        rs += __shfl_xor(rs, 16);
        rs += __shfl_xor(rs, 32);
        lrun = lrun * scl + rs;
        mrun = mnew;

        float sclr[4];
#pragma unroll
        for (int r = 0; r < 4; ++r) sclr[r] = __shfl(scl, quad * 4 + r);
#pragma unroll
        for (int jd = 0; jd < 4; ++jd)
#pragma unroll
            for (int r = 0; r < 4; ++r) oacc[jd][r] *= sclr[r];

#pragma unroll
        for (int js = 0; js < 4; ++js) {
            unsigned p01 = (unsigned)f2bf(sacc[js][0]) | ((unsigned)f2bf(sacc[js][1]) << 16);
            unsigned p23 = (unsigned)f2bf(sacc[js][2]) | ((unsigned)f2bf(sacc[js][3]) << 16);
            *(uint2*)(Ps + myrow + js * 16 + quad * 4) = make_uint2(p01, p23);
        }

#pragma unroll
        for (int ks = 0; ks < 2; ++ks) {
            s8v ap = *(const s8v*)(Ps + myrow + ks * 32 + quad * 8);
#pragma unroll
            for (int jd = 0; jd < 4; ++jd) {
                s8v vf = *(const s8v*)(Vs + (jd * 16 + col16) * PT + ks * 32 + quad * 8);
                oacc[jd] = __builtin_amdgcn_mfma_f32_16x16x32_bf16(ap, vf, oacc[jd], 0, 0, 0);
            }
        }
    }

    const float inv = 1.0f / lrun;
    float invr[4];
#pragma unroll
    for (int r = 0; r < 4; ++r) invr[r] = __shfl(inv, quad * 4 + r);
#pragma unroll
    for (int r = 0; r < 4; ++r) {
        const int t = t0 + w * 16 + quad * 4 + r;
#pragma unroll
        for (int jd = 0; jd < 4; ++jd)
            O[(size_t)(b_ * TT + t) * EE + h * HDIM + jd * 16 + col16] =
                f2bf(oacc[jd][r] * invr[r]);
    }
}

// ---------------------------------------------------------------------------
extern "C" void kernel_launch(void* const* d_in, const int* in_sizes, int n_in,
                              void* d_out, int out_size, void* d_ws, size_t ws_size,
                              hipStream_t stream)
{
    (void)in_sizes; (void)n_in; (void)out_size; (void)ws_size;

    const float* x    = (const float*)d_in[0];
    const float* mask = (const float*)d_in[1];
    const float* Wq   = (const float*)d_in[2];
    const float* bq   = (const float*)d_in[3];
    const float* Wk   = (const float*)d_in[4];
    const float* bk   = (const float*)d_in[5];
    const float* Wv   = (const float*)d_in[6];
    const float* bv   = (const float*)d_in[7];
    const float* Wo   = (const float*)d_in[8];
    const float* bo   = (const float*)d_in[9];
    float* out = (float*)d_out;

    unsigned short* xb  = (unsigned short*)d_ws;
    unsigned short* wqb = xb  + (size_t)MROWS * EE;
    unsigned short* wkb = wqb + (size_t)EE * EE;
    unsigned short* wvb = wkb + (size_t)2 * EE * EE;
    unsigned short* wob = wvb + (size_t)2 * EE * EE;
    unsigned short* mb  = wob + (size_t)EE * EE;
    unsigned short* qp  = mb  + (size_t)BB * TT * TT;
    unsigned short* kp  = qp  + (size_t)MROWS * EE;
    unsigned short* vt  = kp  + (size_t)BB * HH * SS * HDIM;
    unsigned short* ao  = vt  + (size_t)BB * HH * SS * HDIM;

    dim3 blk(256);

    cvt6_kernel<<<4096, blk, 0, stream>>>(x, Wq, Wk, Wv, Wo, mask,
                                          xb, wqb, wkb, wvb, wob, mb);
    gemm_qkv_kernel<<<dim3(1280), blk, 0, stream>>>(
        xb, wqb, wkb, wvb, bq, bk, bv, qp, kp, vt);
    attn_mfma6_kernel<<<dim3(1024), blk, 0, stream>>>(qp, kp, vt, mb, ao);
    gemm_o64_kernel<<<dim3(64, 8), blk, 0, stream>>>(ao, wob, bo, out);
}